// Round 5
// baseline (948.407 us; speedup 1.0000x reference)
//
#include <hip/hip_runtime.h>
#include <hip/hip_cooperative_groups.h>
#include <math.h>

namespace cg = cooperative_groups;

#define B_  4
#define V_  256
#define C1_ 64
#define C2_ 32
#define H0_ 128
#define H2_ 256

typedef short bf16x8 __attribute__((ext_vector_type(8)));
typedef float f32x4  __attribute__((ext_vector_type(4)));

static __device__ __forceinline__ short f2bf(float f) {
    unsigned u = __float_as_uint(f);
    u += 0x7fffu + ((u >> 16) & 1u);          // RNE
    return (short)(u >> 16);
}

// ---------------------------------------------------------------------------
// Shared-memory union: one 32 KB block reused by every phase.
// conv: 18.5 KB | pair_out: 32 KB | node_pre: 1 KB | pair_pre: 0.5 KB
// ---------------------------------------------------------------------------
union SMem {
    struct {
        int list[V_];
        int wc[4];
        __align__(16) short h1[64][136];       // 272 B stride, 16B-aligned
    } conv;
    __align__(16) float4 aj[32 * 64];          // 32 KB, swizzled
    float nx[2 * H0_];                         // node_pre: 2 nodes staging
    float px[H0_];                             // pair_pre staging
};

// ---------------------------------------------------------------------------
// Phase bodies — bit-identical math to the R3 kernels.
// ---------------------------------------------------------------------------
static __device__ __forceinline__ void prep_body(
    int idx, const float* __restrict__ W1c1, const float* __restrict__ W21,
    const float* __restrict__ W1c2, const float* __restrict__ W22,
    short* __restrict__ wsW)
{
    if (idx < 4096) {
        int n = idx >> 5, k = idx & 31;
        wsW[idx] = f2bf(W1c1[k * H0_ + n]);
    } else if (idx < 20480) {
        int t = idx - 4096; int n = t >> 7, k = t & 127;
        wsW[idx] = f2bf(W21[k * H0_ + n]);
    } else if (idx < 24576) {
        int t = idx - 20480; int n = t >> 5, k = t & 31;
        wsW[idx] = f2bf(W1c2[k * H0_ + n]);
    } else if (idx < 40960) {
        int t = idx - 24576; int n = t >> 7, k = t & 127;
        wsW[idx] = f2bf(W22[k * H0_ + n]);
    }
}

// 2 nodes per 256-thread block (halves are independent 128-thread groups;
// inner loop identical to the original 128-thread kernel -> bit-exact).
template <int CIN>
static __device__ __forceinline__ void npre_body(
    int node0, const float* __restrict__ x, const float* __restrict__ W1,
    const float* __restrict__ b1, float* __restrict__ P, float* __restrict__ Q,
    float* __restrict__ sx2)
{
    const int tid  = threadIdx.x;
    const int half = tid >> 7;
    const int n    = tid & 127;
    const int bi   = node0 + half;
    float* sx = sx2 + half * CIN;
    if (n < CIN) sx[n] = x[bi * CIN + n];
    __syncthreads();
    float accP = b1[n], accQ = 0.f;
    #pragma unroll 4
    for (int k = 0; k < CIN; k += 4) {
        float4 xv = *reinterpret_cast<const float4*>(&sx[k]);
        float wa0 = W1[(k + 0) * H0_ + n], wb0 = W1[(CIN + k + 0) * H0_ + n];
        float wa1 = W1[(k + 1) * H0_ + n], wb1 = W1[(CIN + k + 1) * H0_ + n];
        float wa2 = W1[(k + 2) * H0_ + n], wb2 = W1[(CIN + k + 2) * H0_ + n];
        float wa3 = W1[(k + 3) * H0_ + n], wb3 = W1[(CIN + k + 3) * H0_ + n];
        accP = fmaf(xv.x, wa0 - wb0, accP);  accQ = fmaf(xv.x, wb0, accQ);
        accP = fmaf(xv.y, wa1 - wb1, accP);  accQ = fmaf(xv.y, wb1, accQ);
        accP = fmaf(xv.z, wa2 - wb2, accP);  accQ = fmaf(xv.z, wb2, accQ);
        accP = fmaf(xv.w, wa3 - wb3, accP);  accQ = fmaf(xv.w, wb3, accQ);
    }
    P[bi * H0_ + n] = accP;
    Q[bi * H0_ + n] = accQ;
}

// EdgeConvE main (R3 body: v2 structure + ballot list build)
static __device__ void conv_body(
    const int bi, const int* __restrict__ adj, const float* __restrict__ e,
    const float* __restrict__ P, const float* __restrict__ Q,
    const short* __restrict__ W1cT, const short* __restrict__ W2T,
    const float* __restrict__ b2, float* __restrict__ out,
    int* __restrict__ s_list, int* __restrict__ s_wc, short (*s_h1)[136])
{
    const int b    = bi >> 8;
    const int tid  = threadIdx.x;
    const int w    = tid >> 6;
    const int lane = tid & 63;
    const int l15  = lane & 15;
    const int quad = lane >> 4;

    // ballot-based neighbor list (no atomics)
    const int av = adj[bi * V_ + tid];
    unsigned long long bm = __ballot(av > 0);
    if (lane == 0) s_wc[w] = __popcll(bm);
    __syncthreads();
    const int cnt = s_wc[0] + s_wc[1] + s_wc[2] + s_wc[3];
    if (av > 0) {
        int base = 0;
        #pragma unroll
        for (int k = 0; k < 4; ++k) if (k < w) base += s_wc[k];
        int pos = base + __popcll(bm & ((1ull << lane) - 1ull));
        s_list[pos] = tid;
    }
    __syncthreads();
    if (cnt == 0) { if (tid < H0_) out[bi * H0_ + tid] = 0.f; return; }

    // GEMM2 B-fragments: wave w owns N-tiles 2w, 2w+1 -> 8 frags (32 VGPR)
    bf16x8 B2[2][4];
    float bb[2], vmax[2];
    #pragma unroll
    for (int h = 0; h < 2; ++h) {
        const int nt = w * 2 + h;
        #pragma unroll
        for (int kk = 0; kk < 4; ++kk)
            B2[h][kk] = *(const bf16x8*)(W2T + (nt * 16 + l15) * H0_ + kk * 32 + quad * 8);
        bb[h]   = b2[nt * 16 + l15];
        vmax[h] = 0.f;
    }
    float Pp[8];
    #pragma unroll
    for (int nt = 0; nt < 8; ++nt) Pp[nt] = P[bi * H0_ + nt * 16 + l15];

    const int row0 = w * 16;

    // prefetch first pass's e rows
    int ta0 = row0 + l15; if (ta0 >= cnt) ta0 = cnt - 1;
    const float* er0 = e + (bi * V_ + s_list[ta0]) * C2_ + quad * 8;
    float4 e0 = *(const float4*)(er0);
    float4 e1 = *(const float4*)(er0 + 4);

    for (int t0 = 0; t0 < cnt; t0 += 64) {
        const int tb = t0 + row0;

        // A-fragment for GEMM1 from prefetched e: A[m=l15][k=quad*8+j]
        bf16x8 A1;
        A1[0] = f2bf(e0.x); A1[1] = f2bf(e0.y); A1[2] = f2bf(e0.z); A1[3] = f2bf(e0.w);
        A1[4] = f2bf(e1.x); A1[5] = f2bf(e1.y); A1[6] = f2bf(e1.z); A1[7] = f2bf(e1.w);

        // issue next pass's e loads now; they retire under GEMM1+GEMM2
        {
            int tn = t0 + 64 + row0 + l15; if (tn >= cnt) tn = cnt - 1;
            const float* ern = e + (bi * V_ + s_list[tn]) * C2_ + quad * 8;
            e0 = *(const float4*)(ern);
            e1 = *(const float4*)(ern + 4);
        }

        // GEMM1: e @ W1c (K=32, one MFMA per N-tile)
        f32x4 acc[8];
        #pragma unroll
        for (int nt = 0; nt < 8; ++nt) {
            bf16x8 B1 = *(const bf16x8*)(W1cT + (nt * 16 + l15) * C2_ + quad * 8);
            f32x4 z = {0.f, 0.f, 0.f, 0.f};
            acc[nt] = __builtin_amdgcn_mfma_f32_16x16x32_bf16(A1, B1, z, 0, 0, 0);
        }

        // make sure previous pass's GEMM2 readers are done before overwriting
        if (t0 > 0) __syncthreads();

        // epilogue 1: + P[i] + Q[j], relu, bf16 -> LDS (rows = edge slots)
        #pragma unroll
        for (int r = 0; r < 4; ++r) {
            int t = tb + quad * 4 + r; if (t >= cnt) t = cnt - 1;
            const float* Qr = Q + (b * V_ + s_list[t]) * H0_ + l15;
            short* dst = &s_h1[row0 + quad * 4 + r][l15];
            #pragma unroll
            for (int nt = 0; nt < 8; ++nt) {
                float v = acc[nt][r] + Pp[nt] + Qr[nt * 16];
                dst[nt * 16] = f2bf(fmaxf(v, 0.f));
            }
        }

        __syncthreads();

        // GEMM2: h1 @ W2, N-split across waves, M = all 64 edge rows
        #pragma unroll
        for (int mt = 0; mt < 4; ++mt) {
            f32x4 a20 = {0.f,0.f,0.f,0.f}, a21 = {0.f,0.f,0.f,0.f};
            #pragma unroll
            for (int kk = 0; kk < 4; ++kk) {
                bf16x8 A2 = *(const bf16x8*)(&s_h1[mt * 16 + l15][kk * 32 + quad * 8]);
                a20 = __builtin_amdgcn_mfma_f32_16x16x32_bf16(A2, B2[0][kk], a20, 0, 0, 0);
                a21 = __builtin_amdgcn_mfma_f32_16x16x32_bf16(A2, B2[1][kk], a21, 0, 0, 0);
            }
            float m0 = fmaxf(fmaxf(a20[0], a20[1]), fmaxf(a20[2], a20[3]));
            float m1 = fmaxf(fmaxf(a21[0], a21[1]), fmaxf(a21[2], a21[3]));
            vmax[0] = fmaxf(vmax[0], fmaxf(m0 + bb[0], 0.f));
            vmax[1] = fmaxf(vmax[1], fmaxf(m1 + bb[1], 0.f));
        }
    }

    // cross-quad (rows) max, then direct write of this wave's own channels
    #pragma unroll
    for (int h = 0; h < 2; ++h) {
        float p = vmax[h];
        p = fmaxf(p, __shfl_xor(p, 16, 64));
        p = fmaxf(p, __shfl_xor(p, 32, 64));
        if (quad == 0) out[bi * H0_ + (w * 2 + h) * 16 + l15] = p;
    }
}

// pair hoist (original per-node form, 256 threads, bit-exact)
static __device__ __forceinline__ void ppre_body(
    int bi, const float* __restrict__ x2, const float* __restrict__ W3,
    const float* __restrict__ b3, float* __restrict__ Ai, float* __restrict__ Aj,
    float* __restrict__ s_x)
{
    const int n = threadIdx.x;
    if (n < H0_) s_x[n] = x2[bi * H0_ + n];
    __syncthreads();
    float aI = b3[n], aJ = 0.f;
    #pragma unroll 4
    for (int k = 0; k < H0_; k += 4) {
        float4 xv = *reinterpret_cast<const float4*>(&s_x[k]);
        aJ = fmaf(xv.x, W3[(k + 0) * H2_ + n], aJ);
        aJ = fmaf(xv.y, W3[(k + 1) * H2_ + n], aJ);
        aJ = fmaf(xv.z, W3[(k + 2) * H2_ + n], aJ);
        aJ = fmaf(xv.w, W3[(k + 3) * H2_ + n], aJ);
        aI = fmaf(xv.x, W3[(H0_ + k + 0) * H2_ + n], aI);
        aI = fmaf(xv.y, W3[(H0_ + k + 1) * H2_ + n], aI);
        aI = fmaf(xv.z, W3[(H0_ + k + 2) * H2_ + n], aI);
        aI = fmaf(xv.w, W3[(H0_ + k + 3) * H2_ + n], aI);
    }
    Ai[bi * H2_ + n] = aI;
    Aj[bi * H2_ + n] = aJ;
}

// pair output (R3 body: Aj tile staged in LDS with float4 XOR swizzle)
static __device__ __forceinline__ void pout_body(
    int blk, const float* __restrict__ Ai, const float* __restrict__ Aj,
    const float* __restrict__ Wo, const float* __restrict__ bo,
    float* __restrict__ out, float4* __restrict__ s_aj)
{
    const int b    = blk >> 9;
    const int ig   = (blk >> 3) & 63;
    const int jq   = blk & 7;                          // 8 tiles of 32 j
    const int i    = (ig << 2) + (threadIdx.x >> 6);
    const int lane = threadIdx.x & 63;
    const int jj   = lane >> 4;
    const int c    = lane & 15;

    // cooperative stage: 32 rows x 64 float4 (coalesced; write = row-perm)
    const float4* src = (const float4*)(Aj + (b * V_ + jq * 32) * H2_);
    #pragma unroll
    for (int k = 0; k < 8; ++k) {
        int g  = threadIdx.x + k * 256;
        int jr = g >> 6, f = g & 63;
        s_aj[jr * 64 + (f ^ (jr & 7))] = src[g];
    }

    const float* ai = Ai + (b * V_ + i) * H2_ + c * 16;
    float4 a0 = *(const float4*)(ai);
    float4 a1 = *(const float4*)(ai + 4);
    float4 a2 = *(const float4*)(ai + 8);
    float4 a3 = *(const float4*)(ai + 12);
    const float* wo = Wo + c * 16;
    float4 w0 = *(const float4*)(wo);
    float4 w1 = *(const float4*)(wo + 4);
    float4 w2 = *(const float4*)(wo + 8);
    float4 w3 = *(const float4*)(wo + 12);
    const float bo0 = bo[0];

    __syncthreads();

    for (int js = 0; js < 32; js += 4) {
        const int jr = js + jj;
        const float4* arow = &s_aj[jr * 64];
        const int sw = jr & 7, f0 = c * 4;
        float4 q0 = arow[(f0 + 0) ^ sw];
        float4 q1 = arow[(f0 + 1) ^ sw];
        float4 q2 = arow[(f0 + 2) ^ sw];
        float4 q3 = arow[(f0 + 3) ^ sw];
        float p;
        p = fmaxf(a0.x + q0.x, 0.f) * w0.x;
        p = fmaf(fmaxf(a0.y + q0.y, 0.f), w0.y, p);
        p = fmaf(fmaxf(a0.z + q0.z, 0.f), w0.z, p);
        p = fmaf(fmaxf(a0.w + q0.w, 0.f), w0.w, p);
        p = fmaf(fmaxf(a1.x + q1.x, 0.f), w1.x, p);
        p = fmaf(fmaxf(a1.y + q1.y, 0.f), w1.y, p);
        p = fmaf(fmaxf(a1.z + q1.z, 0.f), w1.z, p);
        p = fmaf(fmaxf(a1.w + q1.w, 0.f), w1.w, p);
        p = fmaf(fmaxf(a2.x + q2.x, 0.f), w2.x, p);
        p = fmaf(fmaxf(a2.y + q2.y, 0.f), w2.y, p);
        p = fmaf(fmaxf(a2.z + q2.z, 0.f), w2.z, p);
        p = fmaf(fmaxf(a2.w + q2.w, 0.f), w2.w, p);
        p = fmaf(fmaxf(a3.x + q3.x, 0.f), w3.x, p);
        p = fmaf(fmaxf(a3.y + q3.y, 0.f), w3.y, p);
        p = fmaf(fmaxf(a3.z + q3.z, 0.f), w3.z, p);
        p = fmaf(fmaxf(a3.w + q3.w, 0.f), w3.w, p);
        #pragma unroll
        for (int off = 1; off < 16; off <<= 1)
            p += __shfl_xor(p, off, 64);               // stays within jj group
        if (c == 0)
            out[(b * V_ + i) * V_ + jq * 32 + jr] =
                1.f / (1.f + __builtin_expf(-(p + bo0)));
    }
}

// ---------------------------------------------------------------------------
// The cooperative mega-kernel: 6 phases, 5 grid.sync()s, one launch.
// Grid = 1024 x 256, 32 KB LDS, <=128 VGPR -> 4 blocks/CU co-resident.
// ---------------------------------------------------------------------------
__global__ __launch_bounds__(256, 4) void mega_k(
    const int* __restrict__ adj, const float* __restrict__ xf,
    const float* __restrict__ e,
    const float* __restrict__ ec1W1, const float* __restrict__ ec1W2,
    const float* __restrict__ ec1b1, const float* __restrict__ ec1b2,
    const float* __restrict__ ec2W1, const float* __restrict__ ec2W2,
    const float* __restrict__ ec2b1, const float* __restrict__ ec2b2,
    const float* __restrict__ h3W, const float* __restrict__ h3b,
    const float* __restrict__ oW, const float* __restrict__ ob,
    short* __restrict__ wsW, float* __restrict__ P, float* __restrict__ Q,
    float* __restrict__ x1, float* __restrict__ x2,
    float* __restrict__ Ai, float* __restrict__ Aj, float* __restrict__ out)
{
    __shared__ SMem sm;
    cg::grid_group grid = cg::this_grid();
    const int blk = blockIdx.x;

    // Phase A: node hoist for conv1 (blocks 0-511) || weight prep (512-671)
    if (blk < 512) {
        npre_body<C1_>(blk * 2, xf, ec1W1, ec1b1, P, Q, sm.nx);
    } else if (blk < 672) {
        prep_body((blk - 512) * 256 + threadIdx.x,
                  ec1W1 + 2 * C1_ * H0_, ec1W2,
                  ec2W1 + 2 * H0_ * H0_, ec2W2, wsW);
    }
    grid.sync();

    // Phase B: conv1 (every block = one node)
    conv_body(blk, adj, e, P, Q, wsW, wsW + 4096, ec1b2, x1,
              sm.conv.list, sm.conv.wc, sm.conv.h1);
    grid.sync();

    // Phase C: node hoist for conv2
    if (blk < 512) npre_body<H0_>(blk * 2, x1, ec2W1, ec2b1, P, Q, sm.nx);
    grid.sync();

    // Phase D: conv2
    conv_body(blk, adj, e, P, Q, wsW + 20480, wsW + 24576, ec2b2, x2,
              sm.conv.list, sm.conv.wc, sm.conv.h1);
    grid.sync();

    // Phase E: pair hoist (every block = one node)
    ppre_body(blk, x2, h3W, h3b, Ai, Aj, sm.px);
    grid.sync();

    // Phase F: pair output, 2 tiles per block (grid-stride over 2048)
    for (int it = 0; it < 2; ++it) {
        pout_body(blk + it * 1024, Ai, Aj, oW, ob, out, sm.aj);
        __syncthreads();     // protect s_aj restage / end
    }
}

// ---------------------------------------------------------------------------
// Fallback standalone kernels (R3-equivalent), used only if the cooperative
// launch is rejected at runtime.
// ---------------------------------------------------------------------------
__global__ __launch_bounds__(256) void prep_k(
    const float* __restrict__ W1c1, const float* __restrict__ W21,
    const float* __restrict__ W1c2, const float* __restrict__ W22,
    short* __restrict__ wsW)
{
    prep_body(blockIdx.x * 256 + threadIdx.x, W1c1, W21, W1c2, W22, wsW);
}

template <int CIN>
__global__ __launch_bounds__(256) void npre_k(
    const float* __restrict__ x, const float* __restrict__ W1,
    const float* __restrict__ b1, float* __restrict__ P, float* __restrict__ Q)
{
    __shared__ __align__(16) float sx2[2 * CIN];
    npre_body<CIN>(blockIdx.x * 2, x, W1, b1, P, Q, sx2);
}

__global__ __launch_bounds__(256, 4) void conv_k(
    const int* __restrict__ adj, const float* __restrict__ e,
    const float* __restrict__ P, const float* __restrict__ Q,
    const short* __restrict__ W1cT, const short* __restrict__ W2T,
    const float* __restrict__ b2, float* __restrict__ out)
{
    __shared__ int s_list[V_];
    __shared__ int s_wc[4];
    __shared__ __align__(16) short s_h1[64][136];
    conv_body(blockIdx.x, adj, e, P, Q, W1cT, W2T, b2, out, s_list, s_wc, s_h1);
}

__global__ __launch_bounds__(256) void ppre_k(
    const float* __restrict__ x2, const float* __restrict__ W3,
    const float* __restrict__ b3, float* __restrict__ Ai, float* __restrict__ Aj)
{
    __shared__ __align__(16) float s_x[H0_];
    ppre_body(blockIdx.x, x2, W3, b3, Ai, Aj, s_x);
}

__global__ __launch_bounds__(256) void pout_k(
    const float* __restrict__ Ai, const float* __restrict__ Aj,
    const float* __restrict__ Wo, const float* __restrict__ bo,
    float* __restrict__ out)
{
    __shared__ __align__(16) float4 s_aj[32 * 64];
    pout_body(blockIdx.x, Ai, Aj, Wo, bo, out, s_aj);
}

// ---------------------------------------------------------------------------
extern "C" void kernel_launch(void* const* d_in, const int* in_sizes, int n_in,
                              void* d_out, int out_size, void* d_ws, size_t ws_size,
                              hipStream_t stream) {
    const int*   adj   = (const int*)  d_in[0];
    const float* xf    = (const float*)d_in[1];
    const float* ea    = (const float*)d_in[2];
    const float* ec1W1 = (const float*)d_in[3];
    const float* ec1b1 = (const float*)d_in[4];
    const float* ec1W2 = (const float*)d_in[5];
    const float* ec1b2 = (const float*)d_in[6];
    const float* ec2W1 = (const float*)d_in[7];
    const float* ec2b1 = (const float*)d_in[8];
    const float* ec2W2 = (const float*)d_in[9];
    const float* ec2b2 = (const float*)d_in[10];
    const float* h3W   = (const float*)d_in[11];
    const float* h3b   = (const float*)d_in[12];
    const float* oW    = (const float*)d_in[13];
    const float* ob    = (const float*)d_in[14];
    float* out = (float*)d_out;

    const int NV = B_ * V_;                    // 1024 nodes
    float* x1 = (float*)d_ws;                  // NV*H0
    float* x2 = x1 + NV * H0_;                 // NV*H0
    float* R  = x2 + NV * H0_;                 // reuse region
    float* P  = R;                             // NV*H0
    float* Q  = R + NV * H0_;                  // NV*H0
    float* Ai = R;                             // NV*H2 (P/Q dead by then)
    float* Aj = R + NV * H2_;                  // NV*H2
    short* wsW = (short*)(R + 2 * NV * H2_);   // 40960 bf16 weights
    short* W1cT1 = wsW;
    short* W2T1  = wsW + 4096;
    short* W1cT2 = wsW + 20480;
    short* W2T2  = wsW + 24576;

    // one cooperative launch, 6 phases, 5 grid syncs
    void* args[] = {
        (void*)&adj, (void*)&xf, (void*)&ea,
        (void*)&ec1W1, (void*)&ec1W2, (void*)&ec1b1, (void*)&ec1b2,
        (void*)&ec2W1, (void*)&ec2W2, (void*)&ec2b1, (void*)&ec2b2,
        (void*)&h3W, (void*)&h3b, (void*)&oW, (void*)&ob,
        (void*)&wsW, (void*)&P, (void*)&Q, (void*)&x1, (void*)&x2,
        (void*)&Ai, (void*)&Aj, (void*)&out
    };
    hipError_t err = hipLaunchCooperativeKernel(
        reinterpret_cast<const void*>(&mega_k),
        dim3(1024), dim3(256), args, 0, stream);

    if (err != hipSuccess) {
        // fallback: R3-equivalent 7-launch sequence
        prep_k<<<160, 256, 0, stream>>>(ec1W1 + 2 * C1_ * H0_, ec1W2,
                                        ec2W1 + 2 * H0_ * H0_, ec2W2, wsW);
        npre_k<C1_><<<512, 256, 0, stream>>>(xf, ec1W1, ec1b1, P, Q);
        conv_k<<<NV, 256, 0, stream>>>(adj, ea, P, Q, W1cT1, W2T1, ec1b2, x1);
        npre_k<H0_><<<512, 256, 0, stream>>>(x1, ec2W1, ec2b1, P, Q);
        conv_k<<<NV, 256, 0, stream>>>(adj, ea, P, Q, W1cT2, W2T2, ec2b2, x2);
        ppre_k<<<NV, 256, 0, stream>>>(x2, h3W, h3b, Ai, Aj);
        pout_k<<<2048, 256, 0, stream>>>(Ai, Aj, oW, ob, out);
    }
}

// Round 6
// 185.562 us; speedup vs baseline: 5.1110x; 5.1110x over previous
//
#include <hip/hip_runtime.h>
#include <math.h>

#define B_  4
#define V_  256
#define C1_ 64
#define C2_ 32
#define H0_ 128
#define H2_ 256

typedef short bf16x8 __attribute__((ext_vector_type(8)));
typedef float f32x4  __attribute__((ext_vector_type(4)));

static __device__ __forceinline__ short f2bf(float f) {
    unsigned u = __float_as_uint(f);
    u += 0x7fffu + ((u >> 16) & 1u);          // RNE
    return (short)(u >> 16);
}

// ---------------------------------------------------------------------------
// Weight prep body: transpose + bf16-convert W1c ([32][H0]->[H0][32]) and
// W2 ([H0][H0]->[H0][H0]^T) for both conv layers.
// Layout in wsW (shorts): W1cT1[128*32] | W2T1[128*128] | W1cT2 | W2T2
// ---------------------------------------------------------------------------
static __device__ __forceinline__ void prep_body(
    int idx, const float* __restrict__ W1c1, const float* __restrict__ W21,
    const float* __restrict__ W1c2, const float* __restrict__ W22,
    short* __restrict__ wsW)
{
    if (idx < 4096) {
        int n = idx >> 5, k = idx & 31;
        wsW[idx] = f2bf(W1c1[k * H0_ + n]);
    } else if (idx < 20480) {
        int t = idx - 4096; int n = t >> 7, k = t & 127;
        wsW[idx] = f2bf(W21[k * H0_ + n]);
    } else if (idx < 24576) {
        int t = idx - 20480; int n = t >> 5, k = t & 31;
        wsW[idx] = f2bf(W1c2[k * H0_ + n]);
    } else if (idx < 40960) {
        int t = idx - 24576; int n = t >> 7, k = t & 127;
        wsW[idx] = f2bf(W22[k * H0_ + n]);
    }
}

// ---------------------------------------------------------------------------
// Node hoist, 2 nodes per 256-thread block: halves are independent
// 128-thread groups running the ORIGINAL per-node loop -> bit-exact,
// W1 streamed once per block serves 2 nodes (half the L2 traffic),
// 512 blocks keeps full CU coverage.
// ---------------------------------------------------------------------------
template <int CIN>
static __device__ __forceinline__ void npre_body(
    int node0, const float* __restrict__ x, const float* __restrict__ W1,
    const float* __restrict__ b1, float* __restrict__ P, float* __restrict__ Q,
    float* __restrict__ sx2)
{
    const int tid  = threadIdx.x;
    const int half = tid >> 7;
    const int n    = tid & 127;
    const int bi   = node0 + half;
    float* sx = sx2 + half * CIN;
    if (n < CIN) sx[n] = x[bi * CIN + n];
    __syncthreads();
    float accP = b1[n], accQ = 0.f;
    #pragma unroll 4
    for (int k = 0; k < CIN; k += 4) {
        float4 xv = *reinterpret_cast<const float4*>(&sx[k]);
        float wa0 = W1[(k + 0) * H0_ + n], wb0 = W1[(CIN + k + 0) * H0_ + n];
        float wa1 = W1[(k + 1) * H0_ + n], wb1 = W1[(CIN + k + 1) * H0_ + n];
        float wa2 = W1[(k + 2) * H0_ + n], wb2 = W1[(CIN + k + 2) * H0_ + n];
        float wa3 = W1[(k + 3) * H0_ + n], wb3 = W1[(CIN + k + 3) * H0_ + n];
        accP = fmaf(xv.x, wa0 - wb0, accP);  accQ = fmaf(xv.x, wb0, accQ);
        accP = fmaf(xv.y, wa1 - wb1, accP);  accQ = fmaf(xv.y, wb1, accQ);
        accP = fmaf(xv.z, wa2 - wb2, accP);  accQ = fmaf(xv.z, wb2, accQ);
        accP = fmaf(xv.w, wa3 - wb3, accP);  accQ = fmaf(xv.w, wb3, accQ);
    }
    P[bi * H0_ + n] = accP;
    Q[bi * H0_ + n] = accQ;
}

// ---------------------------------------------------------------------------
// Fused launch 1: blocks 0..159 = weight prep; blocks 160..671 = node hoist
// for conv1 (2 nodes/block).  Independent inputs/outputs.
// ---------------------------------------------------------------------------
__global__ __launch_bounds__(256) void pre1_fused_k(
    const float* __restrict__ W1c1, const float* __restrict__ W21,
    const float* __restrict__ W1c2, const float* __restrict__ W22,
    short* __restrict__ wsW,
    const float* __restrict__ xf, const float* __restrict__ ec1W1,
    const float* __restrict__ ec1b1, float* __restrict__ P, float* __restrict__ Q)
{
    if (blockIdx.x < 160) {
        prep_body(blockIdx.x * 256 + threadIdx.x, W1c1, W21, W1c2, W22, wsW);
    } else {
        __shared__ __align__(16) float sx2[2 * C1_];
        npre_body<C1_>((blockIdx.x - 160) * 2, xf, ec1W1, ec1b1, P, Q, sx2);
    }
}

// standalone 2-node node_pre for conv2 (CIN=128), grid 512
template <int CIN>
__global__ __launch_bounds__(256) void npre2_k(
    const float* __restrict__ x, const float* __restrict__ W1,
    const float* __restrict__ b1, float* __restrict__ P, float* __restrict__ Q)
{
    __shared__ __align__(16) float sx2[2 * CIN];
    npre_body<CIN>(blockIdx.x * 2, x, W1, b1, P, Q, sx2);
}

// ---------------------------------------------------------------------------
// EdgeConvE main — byte-identical to R3 (best-known: v2 structure + ballot
// list build, N-split GEMM2, 4 blocks/CU).
// ---------------------------------------------------------------------------
__global__ __launch_bounds__(256, 4) void conv_mfma_k(
    const int* __restrict__ adj, const float* __restrict__ e,
    const float* __restrict__ P, const float* __restrict__ Q,
    const short* __restrict__ W1cT, const short* __restrict__ W2T,
    const float* __restrict__ b2, float* __restrict__ out)
{
    const int bi   = blockIdx.x;           // b*V + i
    const int b    = bi >> 8;
    const int tid  = threadIdx.x;
    const int w    = tid >> 6;
    const int lane = tid & 63;
    const int l15  = lane & 15;
    const int quad = lane >> 4;

    __shared__ int s_list[V_];
    __shared__ int s_wc[4];
    __shared__ __align__(16) short s_h1[64][136];   // 272 B stride, 16B-aligned

    // ballot-based neighbor list (no atomics)
    const int av = adj[bi * V_ + tid];
    unsigned long long bm = __ballot(av > 0);
    if (lane == 0) s_wc[w] = __popcll(bm);
    __syncthreads();
    const int cnt = s_wc[0] + s_wc[1] + s_wc[2] + s_wc[3];
    if (av > 0) {
        int base = 0;
        #pragma unroll
        for (int k = 0; k < 4; ++k) if (k < w) base += s_wc[k];
        int pos = base + __popcll(bm & ((1ull << lane) - 1ull));
        s_list[pos] = tid;
    }
    __syncthreads();
    if (cnt == 0) { if (tid < H0_) out[bi * H0_ + tid] = 0.f; return; }

    // GEMM2 B-fragments: wave w owns N-tiles 2w, 2w+1 -> 8 frags (32 VGPR)
    bf16x8 B2[2][4];
    float bb[2], vmax[2];
    #pragma unroll
    for (int h = 0; h < 2; ++h) {
        const int nt = w * 2 + h;
        #pragma unroll
        for (int kk = 0; kk < 4; ++kk)
            B2[h][kk] = *(const bf16x8*)(W2T + (nt * 16 + l15) * H0_ + kk * 32 + quad * 8);
        bb[h]   = b2[nt * 16 + l15];
        vmax[h] = 0.f;
    }
    float Pp[8];
    #pragma unroll
    for (int nt = 0; nt < 8; ++nt) Pp[nt] = P[bi * H0_ + nt * 16 + l15];

    const int row0 = w * 16;

    // prefetch first pass's e rows
    int ta0 = row0 + l15; if (ta0 >= cnt) ta0 = cnt - 1;
    const float* er0 = e + (bi * V_ + s_list[ta0]) * C2_ + quad * 8;
    float4 e0 = *(const float4*)(er0);
    float4 e1 = *(const float4*)(er0 + 4);

    for (int t0 = 0; t0 < cnt; t0 += 64) {
        const int tb = t0 + row0;

        // A-fragment for GEMM1 from prefetched e: A[m=l15][k=quad*8+j]
        bf16x8 A1;
        A1[0] = f2bf(e0.x); A1[1] = f2bf(e0.y); A1[2] = f2bf(e0.z); A1[3] = f2bf(e0.w);
        A1[4] = f2bf(e1.x); A1[5] = f2bf(e1.y); A1[6] = f2bf(e1.z); A1[7] = f2bf(e1.w);

        // issue next pass's e loads now; they retire under GEMM1+GEMM2
        {
            int tn = t0 + 64 + row0 + l15; if (tn >= cnt) tn = cnt - 1;
            const float* ern = e + (bi * V_ + s_list[tn]) * C2_ + quad * 8;
            e0 = *(const float4*)(ern);
            e1 = *(const float4*)(ern + 4);
        }

        // GEMM1: e @ W1c (K=32, one MFMA per N-tile; B1 from L1-resident global)
        f32x4 acc[8];
        #pragma unroll
        for (int nt = 0; nt < 8; ++nt) {
            bf16x8 B1 = *(const bf16x8*)(W1cT + (nt * 16 + l15) * C2_ + quad * 8);
            f32x4 z = {0.f, 0.f, 0.f, 0.f};
            acc[nt] = __builtin_amdgcn_mfma_f32_16x16x32_bf16(A1, B1, z, 0, 0, 0);
        }

        // make sure previous pass's GEMM2 readers are done before overwriting
        if (t0 > 0) __syncthreads();

        // epilogue 1: + P[i] + Q[j], relu, bf16 -> LDS (rows = edge slots)
        #pragma unroll
        for (int r = 0; r < 4; ++r) {
            int t = tb + quad * 4 + r; if (t >= cnt) t = cnt - 1;
            const float* Qr = Q + (b * V_ + s_list[t]) * H0_ + l15;
            short* dst = &s_h1[row0 + quad * 4 + r][l15];
            #pragma unroll
            for (int nt = 0; nt < 8; ++nt) {
                float v = acc[nt][r] + Pp[nt] + Qr[nt * 16];
                dst[nt * 16] = f2bf(fmaxf(v, 0.f));
            }
        }

        __syncthreads();

        // GEMM2: h1 @ W2, N-split across waves, M = all 64 edge rows
        #pragma unroll
        for (int mt = 0; mt < 4; ++mt) {
            f32x4 a20 = {0.f,0.f,0.f,0.f}, a21 = {0.f,0.f,0.f,0.f};
            #pragma unroll
            for (int kk = 0; kk < 4; ++kk) {
                bf16x8 A2 = *(const bf16x8*)(&s_h1[mt * 16 + l15][kk * 32 + quad * 8]);
                a20 = __builtin_amdgcn_mfma_f32_16x16x32_bf16(A2, B2[0][kk], a20, 0, 0, 0);
                a21 = __builtin_amdgcn_mfma_f32_16x16x32_bf16(A2, B2[1][kk], a21, 0, 0, 0);
            }
            float m0 = fmaxf(fmaxf(a20[0], a20[1]), fmaxf(a20[2], a20[3]));
            float m1 = fmaxf(fmaxf(a21[0], a21[1]), fmaxf(a21[2], a21[3]));
            vmax[0] = fmaxf(vmax[0], fmaxf(m0 + bb[0], 0.f));
            vmax[1] = fmaxf(vmax[1], fmaxf(m1 + bb[1], 0.f));
        }
    }

    // cross-quad (rows) max, then direct write of this wave's own channels
    #pragma unroll
    for (int h = 0; h < 2; ++h) {
        float p = vmax[h];
        p = fmaxf(p, __shfl_xor(p, 16, 64));
        p = fmaxf(p, __shfl_xor(p, 32, 64));
        if (quad == 0) out[bi * H0_ + (w * 2 + h) * 16 + l15] = p;
    }
}

// ---------------------------------------------------------------------------
// Pair hoist, 2 nodes per 256-thread block: thread n computes BOTH nodes'
// column-n outputs, sharing one W3 stream (268 MB -> 134 MB L2 traffic).
// Per-node fma order identical to original -> bit-exact.  512 blocks.
// ---------------------------------------------------------------------------
__global__ __launch_bounds__(256) void ppre2_k(
    const float* __restrict__ x2, const float* __restrict__ W3,
    const float* __restrict__ b3, float* __restrict__ Ai, float* __restrict__ Aj)
{
    const int nb = blockIdx.x;         // 512 blocks, 2 nodes each
    const int n  = threadIdx.x;        // 256
    __shared__ __align__(16) float s_x[2 * H0_];
    s_x[n] = x2[nb * 2 * H0_ + n];
    __syncthreads();
    const float bv = b3[n];
    float aI0 = bv, aJ0 = 0.f, aI1 = bv, aJ1 = 0.f;
    #pragma unroll 4
    for (int k = 0; k < H0_; k += 4) {
        float4 x0 = *reinterpret_cast<const float4*>(&s_x[k]);
        float4 x1 = *reinterpret_cast<const float4*>(&s_x[H0_ + k]);
        float wj0 = W3[(k + 0) * H2_ + n];
        float wj1 = W3[(k + 1) * H2_ + n];
        float wj2 = W3[(k + 2) * H2_ + n];
        float wj3 = W3[(k + 3) * H2_ + n];
        float wi0 = W3[(H0_ + k + 0) * H2_ + n];
        float wi1 = W3[(H0_ + k + 1) * H2_ + n];
        float wi2 = W3[(H0_ + k + 2) * H2_ + n];
        float wi3 = W3[(H0_ + k + 3) * H2_ + n];
        aJ0 = fmaf(x0.x, wj0, aJ0); aJ0 = fmaf(x0.y, wj1, aJ0);
        aJ0 = fmaf(x0.z, wj2, aJ0); aJ0 = fmaf(x0.w, wj3, aJ0);
        aI0 = fmaf(x0.x, wi0, aI0); aI0 = fmaf(x0.y, wi1, aI0);
        aI0 = fmaf(x0.z, wi2, aI0); aI0 = fmaf(x0.w, wi3, aI0);
        aJ1 = fmaf(x1.x, wj0, aJ1); aJ1 = fmaf(x1.y, wj1, aJ1);
        aJ1 = fmaf(x1.z, wj2, aJ1); aJ1 = fmaf(x1.w, wj3, aJ1);
        aI1 = fmaf(x1.x, wi0, aI1); aI1 = fmaf(x1.y, wi1, aI1);
        aI1 = fmaf(x1.z, wi2, aI1); aI1 = fmaf(x1.w, wi3, aI1);
    }
    const int r0 = nb * 2;
    Ai[r0 * H2_ + n]       = aI0;
    Aj[r0 * H2_ + n]       = aJ0;
    Ai[(r0 + 1) * H2_ + n] = aI1;
    Aj[(r0 + 1) * H2_ + n] = aJ1;
}

// ---------------------------------------------------------------------------
// Pair output — byte-identical to R3: 2048 blocks, Aj tile staged in LDS
// with float4 XOR swizzle.
// ---------------------------------------------------------------------------
__global__ __launch_bounds__(256) void pair_out_k(
    const float* __restrict__ Ai, const float* __restrict__ Aj,
    const float* __restrict__ Wo, const float* __restrict__ bo,
    float* __restrict__ out)
{
    const int blk  = blockIdx.x;                       // 2048 blocks
    const int b    = blk >> 9;
    const int ig   = (blk >> 3) & 63;
    const int jq   = blk & 7;                          // 8 tiles of 32 j
    const int i    = (ig << 2) + (threadIdx.x >> 6);
    const int lane = threadIdx.x & 63;
    const int jj   = lane >> 4;
    const int c    = lane & 15;

    __shared__ __align__(16) float4 s_aj[32 * 64];     // 32 KB, swizzled

    // cooperative stage: 32 rows x 64 float4 (coalesced; write = row-perm)
    const float4* src = (const float4*)(Aj + (b * V_ + jq * 32) * H2_);
    #pragma unroll
    for (int k = 0; k < 8; ++k) {
        int g  = threadIdx.x + k * 256;
        int jr = g >> 6, f = g & 63;
        s_aj[jr * 64 + (f ^ (jr & 7))] = src[g];
    }

    const float* ai = Ai + (b * V_ + i) * H2_ + c * 16;
    float4 a0 = *(const float4*)(ai);
    float4 a1 = *(const float4*)(ai + 4);
    float4 a2 = *(const float4*)(ai + 8);
    float4 a3 = *(const float4*)(ai + 12);
    const float* wo = Wo + c * 16;
    float4 w0 = *(const float4*)(wo);
    float4 w1 = *(const float4*)(wo + 4);
    float4 w2 = *(const float4*)(wo + 8);
    float4 w3 = *(const float4*)(wo + 12);
    const float bo0 = bo[0];

    __syncthreads();

    for (int js = 0; js < 32; js += 4) {
        const int jr = js + jj;
        const float4* arow = &s_aj[jr * 64];
        const int sw = jr & 7, f0 = c * 4;
        float4 q0 = arow[(f0 + 0) ^ sw];
        float4 q1 = arow[(f0 + 1) ^ sw];
        float4 q2 = arow[(f0 + 2) ^ sw];
        float4 q3 = arow[(f0 + 3) ^ sw];
        float p;
        p = fmaxf(a0.x + q0.x, 0.f) * w0.x;
        p = fmaf(fmaxf(a0.y + q0.y, 0.f), w0.y, p);
        p = fmaf(fmaxf(a0.z + q0.z, 0.f), w0.z, p);
        p = fmaf(fmaxf(a0.w + q0.w, 0.f), w0.w, p);
        p = fmaf(fmaxf(a1.x + q1.x, 0.f), w1.x, p);
        p = fmaf(fmaxf(a1.y + q1.y, 0.f), w1.y, p);
        p = fmaf(fmaxf(a1.z + q1.z, 0.f), w1.z, p);
        p = fmaf(fmaxf(a1.w + q1.w, 0.f), w1.w, p);
        p = fmaf(fmaxf(a2.x + q2.x, 0.f), w2.x, p);
        p = fmaf(fmaxf(a2.y + q2.y, 0.f), w2.y, p);
        p = fmaf(fmaxf(a2.z + q2.z, 0.f), w2.z, p);
        p = fmaf(fmaxf(a2.w + q2.w, 0.f), w2.w, p);
        p = fmaf(fmaxf(a3.x + q3.x, 0.f), w3.x, p);
        p = fmaf(fmaxf(a3.y + q3.y, 0.f), w3.y, p);
        p = fmaf(fmaxf(a3.z + q3.z, 0.f), w3.z, p);
        p = fmaf(fmaxf(a3.w + q3.w, 0.f), w3.w, p);
        #pragma unroll
        for (int off = 1; off < 16; off <<= 1)
            p += __shfl_xor(p, off, 64);               // stays within jj group
        if (c == 0)
            out[(b * V_ + i) * V_ + jq * 32 + jr] =
                1.f / (1.f + __builtin_expf(-(p + bo0)));
    }
}

// ---------------------------------------------------------------------------
extern "C" void kernel_launch(void* const* d_in, const int* in_sizes, int n_in,
                              void* d_out, int out_size, void* d_ws, size_t ws_size,
                              hipStream_t stream) {
    const int*   adj   = (const int*)  d_in[0];
    const float* xf    = (const float*)d_in[1];
    const float* ea    = (const float*)d_in[2];
    const float* ec1W1 = (const float*)d_in[3];
    const float* ec1b1 = (const float*)d_in[4];
    const float* ec1W2 = (const float*)d_in[5];
    const float* ec1b2 = (const float*)d_in[6];
    const float* ec2W1 = (const float*)d_in[7];
    const float* ec2b1 = (const float*)d_in[8];
    const float* ec2W2 = (const float*)d_in[9];
    const float* ec2b2 = (const float*)d_in[10];
    const float* h3W   = (const float*)d_in[11];
    const float* h3b   = (const float*)d_in[12];
    const float* oW    = (const float*)d_in[13];
    const float* ob    = (const float*)d_in[14];
    float* out = (float*)d_out;

    const int NV = B_ * V_;                    // 1024 nodes
    float* x1 = (float*)d_ws;                  // NV*H0
    float* x2 = x1 + NV * H0_;                 // NV*H0
    float* R  = x2 + NV * H0_;                 // reuse region
    float* P  = R;                             // NV*H0
    float* Q  = R + NV * H0_;                  // NV*H0
    float* Ai = R;                             // NV*H2 (P/Q dead by then)
    float* Aj = R + NV * H2_;                  // NV*H2
    short* wsW = (short*)(R + 2 * NV * H2_);   // 40960 bf16 weights
    short* W1cT1 = wsW;
    short* W2T1  = wsW + 4096;
    short* W1cT2 = wsW + 20480;
    short* W2T2  = wsW + 24576;

    // launch 1: weight prep (160 blocks) || node hoist conv1 (512 blocks)
    pre1_fused_k<<<672, 256, 0, stream>>>(ec1W1 + 2 * C1_ * H0_, ec1W2,
                                          ec2W1 + 2 * H0_ * H0_, ec2W2, wsW,
                                          xf, ec1W1, ec1b1, P, Q);
    // conv1
    conv_mfma_k<<<NV, 256, 0, stream>>>(adj, ea, P, Q, W1cT1, W2T1, ec1b2, x1);
    // conv2
    npre2_k<H0_><<<512, 256, 0, stream>>>(x1, ec2W1, ec2b1, P, Q);
    conv_mfma_k<<<NV, 256, 0, stream>>>(adj, ea, P, Q, W1cT2, W2T2, ec2b2, x2);
    // pair scoring
    ppre2_k<<<512, 256, 0, stream>>>(x2, h3W, h3b, Ai, Aj);
    pair_out_k<<<2048, 256, 0, stream>>>(Ai, Aj, oW, ob, out);
}